// Round 6
// baseline (1667.937 us; speedup 1.0000x reference)
//
#include <hip/hip_runtime.h>

#define FEAT 28   // features per table row
#define LVL  16   // levels
#define HASH_SIZE 524288u          // T_TABLE (power of two for all hashed levels)

typedef float    f32x4 __attribute__((ext_vector_type(4)));
typedef _Float16 f16x4 __attribute__((ext_vector_type(4)));
typedef _Float16 f16x8 __attribute__((ext_vector_type(8)));

// ---------------------------------------------------------------------------
// Pack one f32 row (28 feats, 112B) -> fp16 64B-padded row. NT on both sides:
// stream-once data must not evict the gather's L2-resident table lines.
// ---------------------------------------------------------------------------
__device__ __forceinline__ void pack_row(const float* __restrict__ memory,
                                         f16x8* __restrict__ wsrow, int r)
{
    const f32x4* src = (const f32x4*)(memory + (size_t)r * FEAT);
    f32x4 a[7];
#pragma unroll
    for (int k = 0; k < 7; ++k) a[k] = __builtin_nontemporal_load(src + k);
    f16x8 o[4];
#pragma unroll
    for (int k = 0; k < 28; ++k) o[k >> 3][k & 7] = (_Float16)a[k >> 2][k & 3];
    o[3][4] = o[3][5] = o[3][6] = o[3][7] = (_Float16)0.0f;
    f16x8* dst = wsrow + (size_t)r * 4;
#pragma unroll
    for (int k = 0; k < 4; ++k) __builtin_nontemporal_store(o[k], dst + k);
}

// ---------------------------------------------------------------------------
// Gather one 64-point chunk of one level. 8 lanes/point (lane j = feats
// [4j,4j+4)), 2 points/thread -> 16 independent 8B gathers. Identical
// numerics to the verified R5 kernel.
// ---------------------------------------------------------------------------
__device__ __forceinline__ void gather_pair(
    const float* __restrict__ inputs, const f16x4* __restrict__ wsrow,
    const int* __restrict__ offsets, const int* __restrict__ res_list,
    const float* __restrict__ side_list, float* __restrict__ out,
    int N, int l, int chunk, int tid)
{
    const int pl = tid >> 3;              // local point 0..31
    const int j  = tid & 7;               // feature slice 0..7 (j==7 is pad)
    const int n0 = chunk * 64 + pl;
    const int n1 = n0 + 32;
    if (n0 >= N) return;
    const int n1c = (n1 < N) ? n1 : n0;

    const int      base = offsets[l];
    const unsigned size = (unsigned)(offsets[l + 1] - base);
    const int r0 = res_list[l * 3 + 0];
    const int r1 = res_list[l * 3 + 1];
    const int r2 = res_list[l * 3 + 2];
    const float side = side_list[l];

    const float bmin0 = -3.0f, bmin1 = -4.0f, bmin2 = -2.0f;  // BOUNDS[:,0]

    const bool direct = (((float)r0 * (float)r1) * (float)r2) <= (float)size;
    const unsigned ur0   = (unsigned)r0;
    const unsigned ur0r1 = (unsigned)(r0 * r1);

    int   idx[2][8];
    float w[2][8];
#pragma unroll
    for (int p = 0; p < 2; ++p) {
        const int n = p ? n1c : n0;
        const float x = inputs[n * 3 + 0];
        const float y = inputs[n * 3 + 1];
        const float z = inputs[n * 3 + 2];
        // IEEE division: must match numpy's floor-cell choice bit-for-bit.
        const float p0 = (x - bmin0) / side;
        const float p1 = (y - bmin1) / side;
        const float p2 = (z - bmin2) / side;
        const float g0 = floorf(p0), g1 = floorf(p1), g2 = floorf(p2);
        const float f0 = p0 - g0, f1 = p1 - g1, f2 = p2 - g2;
        const int i0 = (int)g0, i1 = (int)g1, i2 = (int)g2;
#pragma unroll
        for (int c = 0; c < 8; ++c) {
            const int d0 = (c >> 0) & 1, d1 = (c >> 1) & 1, d2 = (c >> 2) & 1;
            const int c0 = min(max(i0 + d0, 0), r0 - 1);
            const int c1 = min(max(i1 + d1, 0), r1 - 1);
            const int c2 = min(max(i2 + d2, 0), r2 - 1);
            const unsigned u0 = (unsigned)c0, u1 = (unsigned)c1,
                           u2 = (unsigned)c2;
            const unsigned didx = u0 + u1 * ur0 + u2 * ur0r1;
            const unsigned hidx =
                (u0 * 1u ^ u1 * 2654435761u ^ u2 * 805459861u) &
                (HASH_SIZE - 1u);
            idx[p][c] = (int)(direct ? didx : hidx) + base;
            float ww = (d0 ? f0 : 1.0f - f0) * (d1 ? f1 : 1.0f - f1);
            ww *= (d2 ? f2 : 1.0f - f2);
            w[p][c] = ww;
        }
    }

    f16x4 v[2][8];
#pragma unroll
    for (int c = 0; c < 8; ++c) {
        v[0][c] = wsrow[(size_t)idx[0][c] * 8 + j];
        v[1][c] = wsrow[(size_t)idx[1][c] * 8 + j];
    }

    f32x4 acc0 = (f32x4)(0.0f), acc1 = (f32x4)(0.0f);
#pragma unroll
    for (int c = 0; c < 8; ++c) {
        const float w0 = w[0][c], w1 = w[1][c];
#pragma unroll
        for (int k = 0; k < 4; ++k) {
            acc0[k] += w0 * (float)v[0][c][k];
            acc1[k] += w1 * (float)v[1][c][k];
        }
    }

    if (j < 7) {
        float* op0 = out + ((size_t)n0 * LVL + l) * (size_t)FEAT + j * 4;
        __builtin_nontemporal_store(acc0, (f32x4*)op0);
        if (n1 < N) {
            float* op1 = out + ((size_t)n1 * LVL + l) * (size_t)FEAT + j * 4;
            __builtin_nontemporal_store(acc1, (f32x4*)op1);
        }
    }
}

// ---------------------------------------------------------------------------
// Fused pipeline stage: blocks with (bid & mask)==0 pack levels
// {packFirst, packFirst+1} (needed by the NEXT launch); the rest gather
// levels {gatherFirst, gatherFirst+1}. Kernel boundary = producer/consumer
// sync. Pack role is interleaved across CUs via the low bits of bid.
// ---------------------------------------------------------------------------
__global__ __launch_bounds__(256) void fused_kernel(
    const float* __restrict__ inputs, const float* __restrict__ memory,
    void* __restrict__ ws, const int* __restrict__ offsets,
    const int* __restrict__ res_list, const float* __restrict__ side_list,
    float* __restrict__ out, int N, int packFirst, int gatherFirst,
    int shift, int G)
{
    const int bid  = blockIdx.x;
    const int tid  = threadIdx.x;
    const int mask = (1 << shift) - 1;

    if ((bid & mask) == 0) {
        if (packFirst < 0) return;
        const int rBeg   = offsets[packFirst];
        const int rEnd   = offsets[packFirst + 2];
        const int packId = bid >> shift;
        const int nPack  = G >> shift;
        for (int r = rBeg + packId * 256 + tid; r < rEnd; r += nPack * 256)
            pack_row(memory, (f16x8*)ws, r);
    } else {
        if (gatherFirst < 0) return;
        const int gId = bid - (bid >> shift) - 1;
        const int Gg  = G - (G >> shift);
        const int bpl = (N + 63) >> 6;      // 64-point chunks per level
        for (int w = gId; w < 2 * bpl; w += Gg) {
            const int l     = gatherFirst + (w >= bpl ? 1 : 0);
            const int chunk = (w >= bpl) ? w - bpl : w;
            gather_pair(inputs, (const f16x4*)ws, offsets, res_list,
                        side_list, out, N, l, chunk, tid);
        }
    }
}

// ---------------------------------------------------------------------------
// Fallback (ws too small): R3 kernel — 7 lanes/point, f32 table.
// ---------------------------------------------------------------------------
__global__ __launch_bounds__(448) void hashgrid_f32_kernel(
    const float* __restrict__ inputs, const float* __restrict__ memory,
    const int* __restrict__ offsets, const int* __restrict__ res_list,
    const float* __restrict__ side_list, float* __restrict__ out, int N)
{
    const int l   = blockIdx.y;
    const int tid = threadIdx.x;
    const int pl  = tid / 7;
    const int j   = tid - pl * 7;
    const int n   = blockIdx.x * 64 + pl;
    if (n >= N) return;

    const int      base = offsets[l];
    const unsigned size = (unsigned)(offsets[l + 1] - base);
    const int r0 = res_list[l * 3 + 0];
    const int r1 = res_list[l * 3 + 1];
    const int r2 = res_list[l * 3 + 2];
    const float side = side_list[l];
    const float bmin0 = -3.0f, bmin1 = -4.0f, bmin2 = -2.0f;

    const float x = inputs[n * 3 + 0];
    const float y = inputs[n * 3 + 1];
    const float z = inputs[n * 3 + 2];
    const float p0 = (x - bmin0) / side;
    const float p1 = (y - bmin1) / side;
    const float p2 = (z - bmin2) / side;
    const float g0 = floorf(p0), g1 = floorf(p1), g2 = floorf(p2);
    const float f0 = p0 - g0, f1 = p1 - g1, f2 = p2 - g2;
    const int i0 = (int)g0, i1 = (int)g1, i2 = (int)g2;

    const bool direct = (((float)r0 * (float)r1) * (float)r2) <= (float)size;
    const unsigned ur0   = (unsigned)r0;
    const unsigned ur0r1 = (unsigned)(r0 * r1);

    int idx8[8]; float w8[8];
#pragma unroll
    for (int c = 0; c < 8; ++c) {
        const int d0 = (c >> 0) & 1, d1 = (c >> 1) & 1, d2 = (c >> 2) & 1;
        const int c0 = min(max(i0 + d0, 0), r0 - 1);
        const int c1 = min(max(i1 + d1, 0), r1 - 1);
        const int c2 = min(max(i2 + d2, 0), r2 - 1);
        const unsigned u0 = (unsigned)c0, u1 = (unsigned)c1, u2 = (unsigned)c2;
        const unsigned didx = u0 + u1 * ur0 + u2 * ur0r1;
        const unsigned hidx =
            (u0 * 1u ^ u1 * 2654435761u ^ u2 * 805459861u) % size;
        idx8[c] = (int)(direct ? didx : hidx) + base;
        float w = (d0 ? f0 : 1.0f - f0) * (d1 ? f1 : 1.0f - f1);
        w *= (d2 ? f2 : 1.0f - f2);
        w8[c] = w;
    }
    f32x4 v[8];
#pragma unroll
    for (int c = 0; c < 8; ++c)
        v[c] = ((const f32x4*)(memory + (size_t)idx8[c] * FEAT))[j];
    f32x4 acc = (f32x4)(0.0f);
#pragma unroll
    for (int c = 0; c < 8; ++c) acc += w8[c] * v[c];
    f32x4* op = (f32x4*)(out + ((size_t)n * LVL + l) * (size_t)FEAT) + j;
    __builtin_nontemporal_store(acc, op);
}

extern "C" void kernel_launch(void* const* d_in, const int* in_sizes, int n_in,
                              void* d_out, int out_size, void* d_ws, size_t ws_size,
                              hipStream_t stream) {
    const float* inputs    = (const float*)d_in[0];
    const float* memory    = (const float*)d_in[1];
    const int*   offsets   = (const int*)d_in[2];
    const int*   res_list  = (const int*)d_in[3];
    const float* side_list = (const float*)d_in[4];
    float* out = (float*)d_out;

    const int N     = in_sizes[0] / 3;      // points
    const int nrows = in_sizes[1] / FEAT;   // total table rows (~5.8M)
    const size_t ws_needed = (size_t)nrows * 64;

    if (ws_size >= ws_needed) {
        // 9-stage pipeline over 8 level-pairs:
        // k0: pack{0,1}; k1..k7: gather{2k-2,2k-1} || pack{2k,2k+1};
        // k8: gather{14,15}.
        // shift: pack-role density. 0 -> all blocks pack; 2 -> 1/4; 4 -> 1/16
        // (small pack batches need few blocks; hashed batches get 1/4).
        static const int packF[9]  = { 0,  2,  4,  6,  8, 10, 12, 14, -1};
        static const int gathF[9]  = {-1,  0,  2,  4,  6,  8, 10, 12, 14};
        static const int shifts[9] = { 0,  4,  2,  2,  2,  2,  2,  2,  4};
        const int G = 2048;
        for (int k = 0; k < 9; ++k) {
            hipLaunchKernelGGL(fused_kernel, dim3(G), dim3(256), 0, stream,
                               inputs, memory, d_ws, offsets, res_list,
                               side_list, out, N, packF[k], gathF[k],
                               shifts[k], G);
        }
    } else {
        dim3 gb(448), gg((N + 63) / 64, LVL);
        hipLaunchKernelGGL(hashgrid_f32_kernel, gg, gb, 0, stream,
                           inputs, memory, offsets, res_list, side_list, out, N);
    }
}